// Round 6
// baseline (803.157 us; speedup 1.0000x reference)
//
#include <hip/hip_runtime.h>

// ---------------- problem constants ----------------
#define T_TOK 16384
#define DM    512
#define DFF   2048
#define NE    8
#define NP    16
#define KP    4
#define RANK  64
#define KR    256           // KP * RANK
#define EPSF  1e-8f
#define CAP   6144          // per-expert pair capacity (expected ~4096)
#define MT_E  48            // CAP / 128 M-tiles per expert

typedef unsigned short u16;
typedef __bf16 bf16x8 __attribute__((ext_vector_type(8)));
typedef float  f32x4  __attribute__((ext_vector_type(4)));
typedef unsigned short u16x8v __attribute__((ext_vector_type(8)));
typedef unsigned short u16x4v __attribute__((ext_vector_type(4)));

typedef __attribute__((address_space(3))) void as3_void;
typedef __attribute__((address_space(1))) void as1_void;

__device__ __forceinline__ u16 f2bf(float f) {
  unsigned int u = __builtin_bit_cast(unsigned int, f);
  u += 0x7fffu + ((u >> 16) & 1u);          // round-to-nearest-even
  return (u16)(u >> 16);
}
__device__ __forceinline__ float bf2f(u16 v) {
  unsigned int u = ((unsigned int)v) << 16;
  return __builtin_bit_cast(float, u);
}

__device__ __forceinline__ void gl_lds16(const u16* g, u16* l) {
  __builtin_amdgcn_global_load_lds((as1_void*)g, (as3_void*)l, 16, 0, 0);
}

// stage 128x64 bf16 tile into contig LDS — 256-thread version (4 rounds)
__device__ __forceinline__ void stage_tile(const u16* g, int ld, u16* lds_tile, int tid) {
  int row = tid >> 3, c8 = (tid & 7) * 8;
#pragma unroll
  for (int ri = 0; ri < 4; ri++)
    gl_lds16(g + (size_t)(ri * 32 + row) * ld + c8, &lds_tile[(ri * 32 + row) * 64 + c8]);
}
// 512-thread version (2 rounds)
__device__ __forceinline__ void stage512(const u16* g, int ld, u16* lds_tile, int tid) {
  int row = tid >> 3, c8 = (tid & 7) * 8;
#pragma unroll
  for (int ri = 0; ri < 2; ri++)
    gl_lds16(g + (size_t)(ri * 64 + row) * ld + c8, &lds_tile[(ri * 64 + row) * 64 + c8]);
}

// shared 128x128 MFMA inner step over one BK=64 LDS tile pair (256-thr kernels)
__device__ __forceinline__ void mfma_block(const u16* As, const u16* Bs, f32x4 acc[4][4],
                                           int wm, int wn, int ln, int quad) {
#pragma unroll
  for (int ks = 0; ks < 2; ks++) {
    bf16x8 af[4], bf[4];
#pragma unroll
    for (int mt = 0; mt < 4; mt++)
      af[mt] = *(const bf16x8*)&As[(wm * 64 + mt * 16 + ln) * 64 + ks * 32 + quad * 8];
#pragma unroll
    for (int nt = 0; nt < 4; nt++)
      bf[nt] = *(const bf16x8*)&Bs[(wn * 64 + nt * 16 + ln) * 64 + ks * 32 + quad * 8];
#pragma unroll
    for (int mt = 0; mt < 4; mt++)
#pragma unroll
      for (int nt = 0; nt < 4; nt++)
        acc[mt][nt] = __builtin_amdgcn_mfma_f32_16x16x32_bf16(af[mt], bf[nt], acc[mt][nt], 0, 0, 0);
  }
}

// ---------------- zero counters (out no longer needs zeroing: gather overwrites) ----
__global__ void zero_kernel(int* __restrict__ cnt, float* __restrict__ probsum) {
  int i = blockIdx.x * 256 + threadIdx.x;
  if (i < NE) cnt[i] = 0;
  if (i >= NE && i < NE + NE * 64) probsum[i - NE] = 0.f;
}

// ---------------- primitive-bank softmax + top-4 ----------------
__global__ void compose_meta(const float* __restrict__ fc1, const float* __restrict__ fc2,
                             float* __restrict__ sw1, int* __restrict__ idx1,
                             float* __restrict__ sw2, int* __restrict__ idx2) {
  int tid = threadIdx.x;
  if (tid >= 16) return;
  const float* src = (tid < 8) ? fc1 : fc2;
  float* sw = (tid < 8) ? sw1 : sw2;
  int*  idx = (tid < 8) ? idx1 : idx2;
  int e = tid & 7;
  float wv[NP];
  float mx = -1e30f;
  for (int p = 0; p < NP; p++) { wv[p] = src[e * NP + p]; mx = fmaxf(mx, wv[p]); }
  float sum = 0.f;
  for (int p = 0; p < NP; p++) { wv[p] = __expf(wv[p] - mx); sum += wv[p]; }
  float inv = 1.f / sum;
  for (int p = 0; p < NP; p++) wv[p] *= inv;
  float tw[KP]; int ti[KP];
  for (int k = 0; k < KP; k++) {
    int best = 0; float bv = -1.f;
    for (int p = 0; p < NP; p++) if (wv[p] > bv) { bv = wv[p]; best = p; }
    tw[k] = bv; ti[k] = best; wv[best] = -2.f;
  }
  float ts = tw[0] + tw[1] + tw[2] + tw[3];
  float invt = 1.f / (ts + EPSF);
  for (int k = 0; k < KP; k++) {
    sw[e * KP + k] = sqrtf(tw[k] * invt + EPSF);
    idx[e * KP + k] = ti[k];
  }
}

// ---------------- build W1/W2 via LDS transpose (coalesced reads AND writes) -------
// A: (P, D, 64) fp32 -> W: (NE, 4*64, D) bf16, W[e][k*64+r][d] = A[p][d][r]*s
__global__ __launch_bounds__(256) void build_AT(
    const float* __restrict__ A, const int* __restrict__ idx,
    const float* __restrict__ sw, u16* __restrict__ W, int D) {
  __shared__ u16 T[64 * 68];
  int ntile = D >> 6;
  int dt = blockIdx.x % ntile;
  int g  = blockIdx.x / ntile;      // e*4+k
  int p = idx[g]; float s = sw[g];
  int d0 = dt * 64;
  int tid = threadIdx.x;
  {
    int rr = (tid & 15) * 4, dd = tid >> 4;
#pragma unroll
    for (int pass = 0; pass < 4; pass++) {
      int d = pass * 16 + dd;
      float4 v = *(const float4*)(A + ((size_t)p * D + d0 + d) * 64 + rr);
      T[(rr + 0) * 68 + d] = f2bf(v.x * s);
      T[(rr + 1) * 68 + d] = f2bf(v.y * s);
      T[(rr + 2) * 68 + d] = f2bf(v.z * s);
      T[(rr + 3) * 68 + d] = f2bf(v.w * s);
    }
  }
  __syncthreads();
  int e = g >> 2, k = g & 3;
  int c = (tid & 15) * 4, r = tid >> 4;
#pragma unroll
  for (int pass = 0; pass < 4; pass++) {
    int rr = pass * 16 + r;
    u16x4v o;
#pragma unroll
    for (int j = 0; j < 4; j++) o[j] = T[rr * 68 + c + j];
    *(u16x4v*)&W[((size_t)e * KR + k * 64 + rr) * D + d0 + c] = o;
  }
}

// ---------------- build V1/V2 (already coalesced elementwise) ----------------
__global__ void build_V(const float* __restrict__ B1, const float* __restrict__ B2,
                        const float* __restrict__ sw1, const int* __restrict__ idx1,
                        const float* __restrict__ sw2, const int* __restrict__ idx2,
                        u16* __restrict__ V1, u16* __restrict__ V2) {
  const int S2 = NE * DFF * KR;   // 4194304  V1[e][f][kr] = B1[p][r][f]*s
  const int S4 = NE * DM * KR;    // 1048576  V2[e][d][kr] = B2[p][r][d]*s
  int i = blockIdx.x * 256 + threadIdx.x;
  if (i < S2) {
    int kr = i & 255; int f = (i >> 8) & 2047; int e = i >> 19;
    int k = kr >> 6, r = kr & 63; int p = idx1[e * 4 + k];
    V1[i] = f2bf(B1[((size_t)p * RANK + r) * DFF + f] * sw1[e * 4 + k]);
  } else if (i < S2 + S4) {
    int j = i - S2;
    int kr = j & 255; int d = (j >> 8) & 511; int e = j >> 17;
    int k = kr >> 6, r = kr & 63; int p = idx2[e * 4 + k];
    V2[j] = f2bf(B2[((size_t)p * RANK + r) * DM + d] * sw2[e * 4 + k]);
  }
}

// ---------------- router, token-per-lane (k-split 4) ----------------
__global__ __launch_bounds__(256) void router_kernel(
    const float* __restrict__ x, const float* __restrict__ Wr,
    float* __restrict__ probsum, int* __restrict__ eidx,
    float* __restrict__ gate) {
  __shared__ float wr_s[NE * 4 * 132];
  __shared__ float ps_s[NE];
  int tid = threadIdx.x;
  if (tid < NE) ps_s[tid] = 0.f;
  for (int i = tid; i < NE * DM; i += 256) {
    int e = i >> 9, k = i & 511;
    wr_s[(e * 4 + (k >> 7)) * 132 + (k & 127)] = Wr[i];
  }
  __syncthreads();
  int lane = tid & 63, wv = tid >> 6;
  int tl = lane & 15, sl = lane >> 4;
  int t = blockIdx.x * 64 + wv * 16 + tl;
  const float* xp = x + (size_t)t * DM + sl * 128;
  const float* wp = &wr_s[sl * 132];
  float acc[NE];
#pragma unroll
  for (int e = 0; e < NE; e++) acc[e] = 0.f;
  for (int c = 0; c < 32; c++) {
    float4 xv = *(const float4*)(xp + c * 4);
#pragma unroll
    for (int e = 0; e < NE; e++) {
      float4 w4 = *(const float4*)(wp + e * 4 * 132 + c * 4);
      acc[e] += xv.x * w4.x + xv.y * w4.y + xv.z * w4.z + xv.w * w4.w;
    }
  }
#pragma unroll
  for (int e = 0; e < NE; e++) {
    acc[e] += __shfl_xor(acc[e], 16, 64);
    acc[e] += __shfl_xor(acc[e], 32, 64);
  }
  if (sl == 0) {
    float mx = acc[0];
#pragma unroll
    for (int e = 1; e < NE; e++) mx = fmaxf(mx, acc[e]);
    float pe[NE]; float sum = 0.f;
#pragma unroll
    for (int e = 0; e < NE; e++) { pe[e] = __expf(acc[e] - mx); sum += pe[e]; }
    float inv = 1.f / sum;
#pragma unroll
    for (int e = 0; e < NE; e++) pe[e] *= inv;
    int i0 = 0;
#pragma unroll
    for (int e = 1; e < NE; e++) if (pe[e] > pe[i0]) i0 = e;
    int i1 = (i0 == 0) ? 1 : 0;
#pragma unroll
    for (int e = 0; e < NE; e++) if (e != i0 && pe[e] > pe[i1]) i1 = e;
    float p0 = pe[i0], p1 = pe[i1];
    float gd = 1.f / (p0 + p1 + EPSF);
    eidx[t] = i0 | (i1 << 3);
    gate[i0 * T_TOK + t] = p0 * gd;
    gate[i1 * T_TOK + t] = p1 * gd;
#pragma unroll
    for (int e = 0; e < NE; e++) atomicAdd(&ps_s[e], pe[e]);
  }
  __syncthreads();
  if (tid < NE) atomicAdd(&probsum[tid * 64 + (blockIdx.x & 63)], ps_s[tid]);
}

// ---------------- scatter (block-aggregated cnt) + per-token slot pairs ----------
__global__ void scatter_kernel(const int* __restrict__ eidx,
                               int* __restrict__ cnt, int* __restrict__ perm,
                               int* __restrict__ slots) {
  __shared__ int hist[NE], base[NE];
  int tid = threadIdx.x;
  if (tid < NE) hist[tid] = 0;
  __syncthreads();
  int t = blockIdx.x * 256 + tid;
  int pk = eidx[t];
  int e0 = pk & 7, e1 = (pk >> 3) & 7;
  int p0 = atomicAdd(&hist[e0], 1);
  int p1 = atomicAdd(&hist[e1], 1);
  __syncthreads();
  if (tid < NE) base[tid] = atomicAdd(&cnt[tid], hist[tid]);
  __syncthreads();
  int g0 = base[e0] + p0; if (g0 >= CAP) g0 = CAP - 1;   // safety (cnt>CAP is ~30 sigma)
  int g1 = base[e1] + p1; if (g1 >= CAP) g1 = CAP - 1;
  perm[e0 * T_TOK + g0] = t;
  perm[e1 * T_TOK + g1] = t;
  slots[t * 2]     = e0 * CAP + g0;
  slots[t * 2 + 1] = e1 * CAP + g1;
}

// ---------------- aux loss (one wave) ----------------
__global__ void aux_kernel(const int* __restrict__ cnt, const float* __restrict__ probsum,
                           float* __restrict__ aux_out) {
  int lane = threadIdx.x;
  if (lane >= 64) return;
  float s[NE];
#pragma unroll
  for (int e = 0; e < NE; e++) {
    float v = probsum[e * 64 + lane];
#pragma unroll
    for (int off = 32; off > 0; off >>= 1) v += __shfl_xor(v, off, 64);
    s[e] = v;
  }
  if (lane == 0) {
    float c[NE]; float cs = 0.f;
    for (int e = 0; e < NE; e++) { c[e] = (float)cnt[e]; cs += c[e]; }
    float aux = 0.f;
    for (int e = 0; e < NE; e++)
      aux += (c[e] / (cs + EPSF)) * (s[e] / (float)T_TOK);
    *aux_out = (float)NE * aux;
  }
}

// ================= FFN pipeline =================
// K1: u[slot,256] = bf16( gather(x) @ A1c )   (unchanged)
__global__ __launch_bounds__(256) void k1_u(
    const float* __restrict__ x, const int* __restrict__ cnt,
    const int* __restrict__ perm, const u16* __restrict__ W1,
    u16* __restrict__ u) {
  __shared__ __align__(16) u16 As[8192], Bs[8192];
  __shared__ int tok_s[128];
  int bid = blockIdx.x;
  int ntile = bid & 1, gm = bid >> 1;
  int e = gm / MT_E, mt = gm % MT_E;
  int m0 = mt << 7;
  int cntE = cnt[e];
  if (m0 >= cntE) return;
  int tid = threadIdx.x;
  if (tid < 128) {
    int mm = m0 + tid; if (mm > cntE - 1) mm = cntE - 1;
    tok_s[tid] = perm[e * T_TOK + mm];
  }
  __syncthreads();
  const u16* Bbase = W1 + (size_t)e * KR * DM + (size_t)(ntile * 128) * DM;
  int wv = tid >> 6, lane = tid & 63;
  int wm = wv >> 1, wn = wv & 1, ln = lane & 15, quad = lane >> 4;
  f32x4 acc[4][4];
#pragma unroll
  for (int a = 0; a < 4; a++)
#pragma unroll
    for (int b = 0; b < 4; b++) acc[a][b] = (f32x4){0.f, 0.f, 0.f, 0.f};
  for (int k0 = 0; k0 < DM; k0 += 64) {
    for (int i = tid; i < 2048; i += 256) {
      int row = i >> 4, c4 = i & 15;
      float4 v = *(const float4*)(x + (size_t)tok_s[row] * DM + k0 + c4 * 4);
      u16x4v o; o[0] = f2bf(v.x); o[1] = f2bf(v.y); o[2] = f2bf(v.z); o[3] = f2bf(v.w);
      *(u16x4v*)&As[row * 64 + c4 * 4] = o;
    }
    stage_tile(Bbase + k0, DM, Bs, tid);
    __syncthreads();
    mfma_block(As, Bs, acc, wm, wn, ln, quad);
    __syncthreads();
  }
  int slot0 = e * CAP + m0;
#pragma unroll
  for (int mt2 = 0; mt2 < 4; mt2++)
#pragma unroll
    for (int nt = 0; nt < 4; nt++)
#pragma unroll
      for (int r = 0; r < 4; r++) {
        int row = wm * 64 + mt2 * 16 + quad * 4 + r;
        int col = ntile * 128 + wn * 64 + nt * 16 + ln;
        u[(size_t)(slot0 + row) * KR + col] = f2bf(acc[mt2][nt][r]);
      }
}

// K23: fused  t[slot, ntile*128 .. +128] = gelu(u @ B1c) @ A2c[:, half]
// 512 thr, u-tile LDS-resident; h never leaves LDS; t accumulated in regs.
__global__ __launch_bounds__(512, 1) void k23(
    const u16* __restrict__ u, const int* __restrict__ cnt,
    const u16* __restrict__ V1, const u16* __restrict__ W2,
    u16* __restrict__ t) {
  __shared__ __align__(16) u16 Us[128 * 256];   // 64 KB
  __shared__ __align__(16) u16 Bs[128 * 64];    // 16 KB
  __shared__ __align__(16) u16 Hs[128 * 128];   // 32 KB
  int bid = blockIdx.x;
  int ntile = bid & 1, gm = bid >> 1;
  int e = gm / MT_E, mt = gm % MT_E;
  int m0 = mt << 7;
  int cntE = cnt[e];
  if (m0 >= cntE) return;
  int tid = threadIdx.x;
  int slot0 = e * CAP + m0;
  const u16* ub  = u + (size_t)slot0 * KR;
  const u16* V1e = V1 + (size_t)e * DFF * KR;
  const u16* W2e = W2 + (size_t)e * KR * DFF + (size_t)(ntile * 128) * DFF;
  {
    int row = tid >> 5, c8 = (tid & 31) * 8;
#pragma unroll
    for (int ri = 0; ri < 8; ri++)
      gl_lds16(ub + (size_t)(ri * 16 + row) * KR + c8, &Us[(ri * 16 + row) * KR + c8]);
  }
  int wv = tid >> 6, lane = tid & 63;
  int wm = wv & 1, wn = wv >> 1, ln = lane & 15, quad = lane >> 4;
  f32x4 tacc[4][2];
#pragma unroll
  for (int a = 0; a < 4; a++)
#pragma unroll
    for (int b = 0; b < 2; b++) tacc[a][b] = (f32x4){0.f, 0.f, 0.f, 0.f};

  for (int f0 = 0; f0 < DFF; f0 += 128) {
    // ---- k2: h = u @ V1[f0:f0+128, :]^T ----
    f32x4 hacc[4][2];
#pragma unroll
    for (int a = 0; a < 4; a++)
#pragma unroll
      for (int b = 0; b < 2; b++) hacc[a][b] = (f32x4){0.f, 0.f, 0.f, 0.f};
    for (int k0 = 0; k0 < KR; k0 += 64) {
      __syncthreads();                              // Bs free (prev readers done)
      stage512(V1e + (size_t)f0 * KR + k0, KR, Bs, tid);
      __syncthreads();                              // staged (barrier drains vmcnt)
#pragma unroll
      for (int ks = 0; ks < 2; ks++) {
        bf16x8 af[4], bf[2];
#pragma unroll
        for (int mt2 = 0; mt2 < 4; mt2++)
          af[mt2] = *(const bf16x8*)&Us[(wm * 64 + mt2 * 16 + ln) * KR + k0 + ks * 32 + quad * 8];
#pragma unroll
        for (int nt = 0; nt < 2; nt++)
          bf[nt] = *(const bf16x8*)&Bs[(wn * 32 + nt * 16 + ln) * 64 + ks * 32 + quad * 8];
#pragma unroll
        for (int mt2 = 0; mt2 < 4; mt2++)
#pragma unroll
          for (int nt = 0; nt < 2; nt++)
            hacc[mt2][nt] = __builtin_amdgcn_mfma_f32_16x16x32_bf16(af[mt2], bf[nt], hacc[mt2][nt], 0, 0, 0);
      }
    }
    __syncthreads();
    // gelu -> Hs (bf16)
#pragma unroll
    for (int mt2 = 0; mt2 < 4; mt2++)
#pragma unroll
      for (int nt = 0; nt < 2; nt++)
#pragma unroll
        for (int r = 0; r < 4; r++) {
          int row = wm * 64 + mt2 * 16 + quad * 4 + r;
          int col = wn * 32 + nt * 16 + ln;
          float v = hacc[mt2][nt][r];
          float s = 1.f / (1.f + __expf(-1.702f * v));
          Hs[row * 128 + col] = f2bf(v * s);
        }
    __syncthreads();
    // ---- k3: t += h @ W2[half, f0:f0+128]^T ----
    for (int fi = 0; fi < 128; fi += 64) {
      __syncthreads();                              // Bs free
      stage512(W2e + f0 + fi, DFF, Bs, tid);
      __syncthreads();
#pragma unroll
      for (int ks = 0; ks < 2; ks++) {
        bf16x8 af[4], bf[2];
#pragma unroll
        for (int mt2 = 0; mt2 < 4; mt2++)
          af[mt2] = *(const bf16x8*)&Hs[(wm * 64 + mt2 * 16 + ln) * 128 + fi + ks * 32 + quad * 8];
#pragma unroll
        for (int nt = 0; nt < 2; nt++)
          bf[nt] = *(const bf16x8*)&Bs[(wn * 32 + nt * 16 + ln) * 64 + ks * 32 + quad * 8];
#pragma unroll
        for (int mt2 = 0; mt2 < 4; mt2++)
#pragma unroll
          for (int nt = 0; nt < 2; nt++)
            tacc[mt2][nt] = __builtin_amdgcn_mfma_f32_16x16x32_bf16(af[mt2], bf[nt], tacc[mt2][nt], 0, 0, 0);
      }
    }
  }
#pragma unroll
  for (int mt2 = 0; mt2 < 4; mt2++)
#pragma unroll
    for (int nt = 0; nt < 2; nt++)
#pragma unroll
      for (int r = 0; r < 4; r++) {
        int row = wm * 64 + mt2 * 16 + quad * 4 + r;
        int col = ntile * 128 + wn * 32 + nt * 16 + ln;
        t[(size_t)(slot0 + row) * KR + col] = f2bf(tacc[mt2][nt][r]);
      }
}

// K4: y[slot, 512] = gate * (t @ B2c)   (no atomics; coalesced bf16 writes)
__global__ __launch_bounds__(256) void k4_y(
    const u16* __restrict__ t, const int* __restrict__ cnt,
    const int* __restrict__ perm, const float* __restrict__ gate,
    const u16* __restrict__ V2, u16* __restrict__ y) {
  __shared__ __align__(16) u16 As[8192], Bs[8192];
  __shared__ float g_s[128];
  int bid = blockIdx.x;
  int ntile = bid & 3, gm = bid >> 2;
  int e = gm / MT_E, mt = gm % MT_E;
  int m0 = mt << 7;
  int cntE = cnt[e];
  if (m0 >= cntE) return;
  int tid = threadIdx.x;
  if (tid < 128) {
    int mm = m0 + tid; if (mm > cntE - 1) mm = cntE - 1;
    int tk = perm[e * T_TOK + mm];
    g_s[tid] = gate[e * T_TOK + tk];
  }
  __syncthreads();
  int slot0 = e * CAP + m0;
  const u16* Abase = t + (size_t)slot0 * KR;
  const u16* Bbase = V2 + (size_t)e * DM * KR + (size_t)(ntile * 128) * KR;
  int wv = tid >> 6, lane = tid & 63;
  int wm = wv >> 1, wn = wv & 1, ln = lane & 15, quad = lane >> 4;
  f32x4 acc[4][4];
#pragma unroll
  for (int a = 0; a < 4; a++)
#pragma unroll
    for (int b = 0; b < 4; b++) acc[a][b] = (f32x4){0.f, 0.f, 0.f, 0.f};
  for (int k0 = 0; k0 < KR; k0 += 64) {
    stage_tile(Abase + k0, KR, As, tid);
    stage_tile(Bbase + k0, KR, Bs, tid);
    __syncthreads();
    mfma_block(As, Bs, acc, wm, wn, ln, quad);
    __syncthreads();
  }
#pragma unroll
  for (int mt2 = 0; mt2 < 4; mt2++)
#pragma unroll
    for (int nt = 0; nt < 4; nt++)
#pragma unroll
      for (int r = 0; r < 4; r++) {
        int row = wm * 64 + mt2 * 16 + quad * 4 + r;
        int col = ntile * 128 + wn * 64 + nt * 16 + ln;
        y[(size_t)(slot0 + row) * DM + col] = f2bf(acc[mt2][nt][r] * g_s[row]);
      }
}

// gather: out[t] = y[slotA] + y[slotB]
__global__ void gather_kernel(const u16* __restrict__ y, const int* __restrict__ slots,
                              float* __restrict__ out) {
  int idx = blockIdx.x * 256 + threadIdx.x;   // one float4 of out per thread
  int t = idx >> 7, c4 = (idx & 127) * 4;
  int sA = slots[t * 2], sB = slots[t * 2 + 1];
  u16x4v a = *(const u16x4v*)&y[(size_t)sA * DM + c4];
  u16x4v b = *(const u16x4v*)&y[(size_t)sB * DM + c4];
  float4 o;
  o.x = bf2f(a[0]) + bf2f(b[0]);
  o.y = bf2f(a[1]) + bf2f(b[1]);
  o.z = bf2f(a[2]) + bf2f(b[2]);
  o.w = bf2f(a[3]) + bf2f(b[3]);
  *(float4*)&out[(size_t)t * DM + c4] = o;
}

// ---------------- launch ----------------
extern "C" void kernel_launch(void* const* d_in, const int* in_sizes, int n_in,
                              void* d_out, int out_size, void* d_ws, size_t ws_size,
                              hipStream_t stream) {
  const float* x   = (const float*)d_in[0];
  const float* Wr  = (const float*)d_in[1];
  const float* fc1 = (const float*)d_in[2];
  const float* fc2 = (const float*)d_in[3];
  const float* A1  = (const float*)d_in[4];
  const float* B1  = (const float*)d_in[5];
  const float* A2  = (const float*)d_in[6];
  const float* B2  = (const float*)d_in[7];
  float* out = (float*)d_out;

  char* ws = (char*)d_ws;
  float* sw1     = (float*)(ws + 0);
  int*   idx1    = (int*)(ws + 512);
  float* sw2     = (float*)(ws + 1024);
  int*   idx2    = (int*)(ws + 1536);
  int*   cnt     = (int*)(ws + 2048);
  float* probsum = (float*)(ws + 2560);
  int*   eidx    = (int*)(ws + 8192);                      // 64 KB
  int*   slots   = (int*)(ws + 8192 + 65536);              // 128 KB (2 ints/token)
  float* gate    = (float*)(ws + 8192 + 65536 + 131072);   // 512 KB
  int*   perm    = (int*)(ws + 8192 + 65536 + 131072 + 524288); // 512 KB
  u16*   W1      = (u16*)(ws + 8192 + 65536 + 131072 + 2 * 524288);
  u16*   V1      = W1 + 1048576;
  u16*   W2      = V1 + 4194304;
  u16*   V2      = W2 + 4194304;
  char*  endW    = (char*)(V2 + 1048576);
  u16*   u_buf   = (u16*)endW;                               // 49152x256 bf16 = 25.2 MB
  u16*   t_buf   = (u16*)(endW + 25165824);                  // 49152x256 bf16 = 25.2 MB
  u16*   y_buf   = (u16*)(endW + 2 * 25165824);              // 49152x512 bf16 = 50.3 MB

  zero_kernel<<<3, 256, 0, stream>>>(cnt, probsum);
  compose_meta<<<1, 64, 0, stream>>>(fc1, fc2, sw1, idx1, sw2, idx2);
  build_AT<<<32 * (DM / 64), 256, 0, stream>>>(A1, idx1, sw1, W1, DM);    // 256 blocks
  build_AT<<<32 * (DFF / 64), 256, 0, stream>>>(A2, idx2, sw2, W2, DFF);  // 1024 blocks
  build_V<<<20480, 256, 0, stream>>>(B1, B2, sw1, idx1, sw2, idx2, V1, V2);
  router_kernel<<<T_TOK / 64, 256, 0, stream>>>(x, Wr, probsum, eidx, gate);
  scatter_kernel<<<T_TOK / 256, 256, 0, stream>>>(eidx, cnt, perm, slots);
  aux_kernel<<<1, 64, 0, stream>>>(cnt, probsum, out + (out_size - 1));

  k1_u<<<2 * NE * MT_E, 256, 0, stream>>>(x, cnt, perm, W1, u_buf);
  k23<<<2 * NE * MT_E, 512, 0, stream>>>(u_buf, cnt, V1, W2, t_buf);
  k4_y<<<4 * NE * MT_E, 256, 0, stream>>>(t_buf, cnt, perm, gate, V2, y_buf);
  gather_kernel<<<T_TOK * DM / 4 / 256, 256, 0, stream>>>(y_buf, slots, out);
}

// Round 7
// 522.564 us; speedup vs baseline: 1.5370x; 1.5370x over previous
//
#include <hip/hip_runtime.h>

// ---------------- problem constants ----------------
#define T_TOK 16384
#define DM    512
#define DFF   2048
#define NE    8
#define NP    16
#define KP    4
#define RANK  64
#define KR    256           // KP * RANK
#define EPSF  1e-8f
#define CAP   6144          // per-expert pair capacity (expected ~4096)
#define MT_E  48            // CAP / 128 M-tiles per expert

typedef unsigned short u16;
typedef __bf16 bf16x8 __attribute__((ext_vector_type(8)));
typedef float  f32x4  __attribute__((ext_vector_type(4)));
typedef unsigned short u16x8v __attribute__((ext_vector_type(8)));
typedef unsigned short u16x4v __attribute__((ext_vector_type(4)));

typedef __attribute__((address_space(3))) void as3_void;
typedef __attribute__((address_space(1))) void as1_void;

__device__ __forceinline__ u16 f2bf(float f) {
  unsigned int u = __builtin_bit_cast(unsigned int, f);
  u += 0x7fffu + ((u >> 16) & 1u);          // round-to-nearest-even
  return (u16)(u >> 16);
}
__device__ __forceinline__ float bf2f(u16 v) {
  unsigned int u = ((unsigned int)v) << 16;
  return __builtin_bit_cast(float, u);
}

__device__ __forceinline__ void gl_lds16(const u16* g, u16* l) {
  __builtin_amdgcn_global_load_lds((as1_void*)g, (as3_void*)l, 16, 0, 0);
}

// stage 128x64 bf16 tile into contig LDS (global_load_lds, wave-uniform dst)
__device__ __forceinline__ void stage_tile(const u16* g, int ld, u16* lds_tile, int tid) {
  int row = tid >> 3, c8 = (tid & 7) * 8;
#pragma unroll
  for (int ri = 0; ri < 4; ri++)
    gl_lds16(g + (size_t)(ri * 32 + row) * ld + c8, &lds_tile[(ri * 32 + row) * 64 + c8]);
}

// shared 128x128 MFMA inner step over one BK=64 LDS tile pair (256-thr kernels)
__device__ __forceinline__ void mfma_block(const u16* As, const u16* Bs, f32x4 acc[4][4],
                                           int wm, int wn, int ln, int quad) {
#pragma unroll
  for (int ks = 0; ks < 2; ks++) {
    bf16x8 af[4], bf[4];
#pragma unroll
    for (int mt = 0; mt < 4; mt++)
      af[mt] = *(const bf16x8*)&As[(wm * 64 + mt * 16 + ln) * 64 + ks * 32 + quad * 8];
#pragma unroll
    for (int nt = 0; nt < 4; nt++)
      bf[nt] = *(const bf16x8*)&Bs[(wn * 64 + nt * 16 + ln) * 64 + ks * 32 + quad * 8];
#pragma unroll
    for (int mt = 0; mt < 4; mt++)
#pragma unroll
      for (int nt = 0; nt < 4; nt++)
        acc[mt][nt] = __builtin_amdgcn_mfma_f32_16x16x32_bf16(af[mt], bf[nt], acc[mt][nt], 0, 0, 0);
  }
}

// ---------------- zero counters (out needs no zeroing: gather overwrites) ----
__global__ void zero_kernel(int* __restrict__ cnt, float* __restrict__ probsum) {
  int i = blockIdx.x * 256 + threadIdx.x;
  if (i < NE) cnt[i] = 0;
  if (i >= NE && i < NE + NE * 64) probsum[i - NE] = 0.f;
}

// ---------------- primitive-bank softmax + top-4 ----------------
__global__ void compose_meta(const float* __restrict__ fc1, const float* __restrict__ fc2,
                             float* __restrict__ sw1, int* __restrict__ idx1,
                             float* __restrict__ sw2, int* __restrict__ idx2) {
  int tid = threadIdx.x;
  if (tid >= 16) return;
  const float* src = (tid < 8) ? fc1 : fc2;
  float* sw = (tid < 8) ? sw1 : sw2;
  int*  idx = (tid < 8) ? idx1 : idx2;
  int e = tid & 7;
  float wv[NP];
  float mx = -1e30f;
  for (int p = 0; p < NP; p++) { wv[p] = src[e * NP + p]; mx = fmaxf(mx, wv[p]); }
  float sum = 0.f;
  for (int p = 0; p < NP; p++) { wv[p] = __expf(wv[p] - mx); sum += wv[p]; }
  float inv = 1.f / sum;
  for (int p = 0; p < NP; p++) wv[p] *= inv;
  float tw[KP]; int ti[KP];
  for (int k = 0; k < KP; k++) {
    int best = 0; float bv = -1.f;
    for (int p = 0; p < NP; p++) if (wv[p] > bv) { bv = wv[p]; best = p; }
    tw[k] = bv; ti[k] = best; wv[best] = -2.f;
  }
  float ts = tw[0] + tw[1] + tw[2] + tw[3];
  float invt = 1.f / (ts + EPSF);
  for (int k = 0; k < KP; k++) {
    sw[e * KP + k] = sqrtf(tw[k] * invt + EPSF);
    idx[e * KP + k] = ti[k];
  }
}

// ---------------- build W1/W2 via LDS transpose (coalesced reads AND writes) -------
// A: (P, D, 64) fp32 -> W: (NE, 4*64, D) bf16, W[e][k*64+r][d] = A[p][d][r]*s
__global__ __launch_bounds__(256) void build_AT(
    const float* __restrict__ A, const int* __restrict__ idx,
    const float* __restrict__ sw, u16* __restrict__ W, int D) {
  __shared__ u16 T[64 * 68];
  int ntile = D >> 6;
  int dt = blockIdx.x % ntile;
  int g  = blockIdx.x / ntile;      // e*4+k
  int p = idx[g]; float s = sw[g];
  int d0 = dt * 64;
  int tid = threadIdx.x;
  {
    int rr = (tid & 15) * 4, dd = tid >> 4;
#pragma unroll
    for (int pass = 0; pass < 4; pass++) {
      int d = pass * 16 + dd;
      float4 v = *(const float4*)(A + ((size_t)p * D + d0 + d) * 64 + rr);
      T[(rr + 0) * 68 + d] = f2bf(v.x * s);
      T[(rr + 1) * 68 + d] = f2bf(v.y * s);
      T[(rr + 2) * 68 + d] = f2bf(v.z * s);
      T[(rr + 3) * 68 + d] = f2bf(v.w * s);
    }
  }
  __syncthreads();
  int e = g >> 2, k = g & 3;
  int c = (tid & 15) * 4, r = tid >> 4;
#pragma unroll
  for (int pass = 0; pass < 4; pass++) {
    int rr = pass * 16 + r;
    u16x4v o;
#pragma unroll
    for (int j = 0; j < 4; j++) o[j] = T[rr * 68 + c + j];
    *(u16x4v*)&W[((size_t)e * KR + k * 64 + rr) * D + d0 + c] = o;
  }
}

// ---------------- build V1/V2 (already coalesced elementwise) ----------------
__global__ void build_V(const float* __restrict__ B1, const float* __restrict__ B2,
                        const float* __restrict__ sw1, const int* __restrict__ idx1,
                        const float* __restrict__ sw2, const int* __restrict__ idx2,
                        u16* __restrict__ V1, u16* __restrict__ V2) {
  const int S2 = NE * DFF * KR;   // 4194304  V1[e][f][kr] = B1[p][r][f]*s
  const int S4 = NE * DM * KR;    // 1048576  V2[e][d][kr] = B2[p][r][d]*s
  int i = blockIdx.x * 256 + threadIdx.x;
  if (i < S2) {
    int kr = i & 255; int f = (i >> 8) & 2047; int e = i >> 19;
    int k = kr >> 6, r = kr & 63; int p = idx1[e * 4 + k];
    V1[i] = f2bf(B1[((size_t)p * RANK + r) * DFF + f] * sw1[e * 4 + k]);
  } else if (i < S2 + S4) {
    int j = i - S2;
    int kr = j & 255; int d = (j >> 8) & 511; int e = j >> 17;
    int k = kr >> 6, r = kr & 63; int p = idx2[e * 4 + k];
    V2[j] = f2bf(B2[((size_t)p * RANK + r) * DM + d] * sw2[e * 4 + k]);
  }
}

// ---------------- router, token-per-lane (k-split 4) ----------------
__global__ __launch_bounds__(256) void router_kernel(
    const float* __restrict__ x, const float* __restrict__ Wr,
    float* __restrict__ probsum, int* __restrict__ eidx,
    float* __restrict__ gate) {
  __shared__ float wr_s[NE * 4 * 132];
  __shared__ float ps_s[NE];
  int tid = threadIdx.x;
  if (tid < NE) ps_s[tid] = 0.f;
  for (int i = tid; i < NE * DM; i += 256) {
    int e = i >> 9, k = i & 511;
    wr_s[(e * 4 + (k >> 7)) * 132 + (k & 127)] = Wr[i];
  }
  __syncthreads();
  int lane = tid & 63, wv = tid >> 6;
  int tl = lane & 15, sl = lane >> 4;
  int t = blockIdx.x * 64 + wv * 16 + tl;
  const float* xp = x + (size_t)t * DM + sl * 128;
  const float* wp = &wr_s[sl * 132];
  float acc[NE];
#pragma unroll
  for (int e = 0; e < NE; e++) acc[e] = 0.f;
  for (int c = 0; c < 32; c++) {
    float4 xv = *(const float4*)(xp + c * 4);
#pragma unroll
    for (int e = 0; e < NE; e++) {
      float4 w4 = *(const float4*)(wp + e * 4 * 132 + c * 4);
      acc[e] += xv.x * w4.x + xv.y * w4.y + xv.z * w4.z + xv.w * w4.w;
    }
  }
#pragma unroll
  for (int e = 0; e < NE; e++) {
    acc[e] += __shfl_xor(acc[e], 16, 64);
    acc[e] += __shfl_xor(acc[e], 32, 64);
  }
  if (sl == 0) {
    float mx = acc[0];
#pragma unroll
    for (int e = 1; e < NE; e++) mx = fmaxf(mx, acc[e]);
    float pe[NE]; float sum = 0.f;
#pragma unroll
    for (int e = 0; e < NE; e++) { pe[e] = __expf(acc[e] - mx); sum += pe[e]; }
    float inv = 1.f / sum;
#pragma unroll
    for (int e = 0; e < NE; e++) pe[e] *= inv;
    int i0 = 0;
#pragma unroll
    for (int e = 1; e < NE; e++) if (pe[e] > pe[i0]) i0 = e;
    int i1 = (i0 == 0) ? 1 : 0;
#pragma unroll
    for (int e = 0; e < NE; e++) if (e != i0 && pe[e] > pe[i1]) i1 = e;
    float p0 = pe[i0], p1 = pe[i1];
    float gd = 1.f / (p0 + p1 + EPSF);
    eidx[t] = i0 | (i1 << 3);
    gate[i0 * T_TOK + t] = p0 * gd;
    gate[i1 * T_TOK + t] = p1 * gd;
#pragma unroll
    for (int e = 0; e < NE; e++) atomicAdd(&ps_s[e], pe[e]);
  }
  __syncthreads();
  if (tid < NE) atomicAdd(&probsum[tid * 64 + (blockIdx.x & 63)], ps_s[tid]);
}

// ---------------- scatter (block-aggregated cnt) + per-token slot pairs ----------
__global__ void scatter_kernel(const int* __restrict__ eidx,
                               int* __restrict__ cnt, int* __restrict__ perm,
                               int* __restrict__ slots) {
  __shared__ int hist[NE], base[NE];
  int tid = threadIdx.x;
  if (tid < NE) hist[tid] = 0;
  __syncthreads();
  int t = blockIdx.x * 256 + tid;
  int pk = eidx[t];
  int e0 = pk & 7, e1 = (pk >> 3) & 7;
  int p0 = atomicAdd(&hist[e0], 1);
  int p1 = atomicAdd(&hist[e1], 1);
  __syncthreads();
  if (tid < NE) base[tid] = atomicAdd(&cnt[tid], hist[tid]);
  __syncthreads();
  int g0 = base[e0] + p0; if (g0 >= CAP) g0 = CAP - 1;   // safety (cnt>CAP is ~30 sigma)
  int g1 = base[e1] + p1; if (g1 >= CAP) g1 = CAP - 1;
  perm[e0 * T_TOK + g0] = t;
  perm[e1 * T_TOK + g1] = t;
  slots[t * 2]     = e0 * CAP + g0;
  slots[t * 2 + 1] = e1 * CAP + g1;
}

// ---------------- aux loss (one wave) ----------------
__global__ void aux_kernel(const int* __restrict__ cnt, const float* __restrict__ probsum,
                           float* __restrict__ aux_out) {
  int lane = threadIdx.x;
  if (lane >= 64) return;
  float s[NE];
#pragma unroll
  for (int e = 0; e < NE; e++) {
    float v = probsum[e * 64 + lane];
#pragma unroll
    for (int off = 32; off > 0; off >>= 1) v += __shfl_xor(v, off, 64);
    s[e] = v;
  }
  if (lane == 0) {
    float c[NE]; float cs = 0.f;
    for (int e = 0; e < NE; e++) { c[e] = (float)cnt[e]; cs += c[e]; }
    float aux = 0.f;
    for (int e = 0; e < NE; e++)
      aux += (c[e] / (cs + EPSF)) * (s[e] / (float)T_TOK);
    *aux_out = (float)NE * aux;
  }
}

// ================= FFN pipeline =================
// K1: u[slot,256] = bf16( gather(x) @ A1c )
__global__ __launch_bounds__(256) void k1_u(
    const float* __restrict__ x, const int* __restrict__ cnt,
    const int* __restrict__ perm, const u16* __restrict__ W1,
    u16* __restrict__ u) {
  __shared__ __align__(16) u16 As[8192], Bs[8192];
  __shared__ int tok_s[128];
  int bid = blockIdx.x;
  int ntile = bid & 1, gm = bid >> 1;
  int e = gm / MT_E, mt = gm % MT_E;
  int m0 = mt << 7;
  int cntE = cnt[e];
  if (m0 >= cntE) return;
  int tid = threadIdx.x;
  if (tid < 128) {
    int mm = m0 + tid; if (mm > cntE - 1) mm = cntE - 1;
    tok_s[tid] = perm[e * T_TOK + mm];
  }
  __syncthreads();
  const u16* Bbase = W1 + (size_t)e * KR * DM + (size_t)(ntile * 128) * DM;
  int wv = tid >> 6, lane = tid & 63;
  int wm = wv >> 1, wn = wv & 1, ln = lane & 15, quad = lane >> 4;
  f32x4 acc[4][4];
#pragma unroll
  for (int a = 0; a < 4; a++)
#pragma unroll
    for (int b = 0; b < 4; b++) acc[a][b] = (f32x4){0.f, 0.f, 0.f, 0.f};
  for (int k0 = 0; k0 < DM; k0 += 64) {
    for (int i = tid; i < 2048; i += 256) {
      int row = i >> 4, c4 = i & 15;
      float4 v = *(const float4*)(x + (size_t)tok_s[row] * DM + k0 + c4 * 4);
      u16x4v o; o[0] = f2bf(v.x); o[1] = f2bf(v.y); o[2] = f2bf(v.z); o[3] = f2bf(v.w);
      *(u16x4v*)&As[row * 64 + c4 * 4] = o;
    }
    stage_tile(Bbase + k0, DM, Bs, tid);
    __syncthreads();
    mfma_block(As, Bs, acc, wm, wn, ln, quad);
    __syncthreads();
  }
  int slot0 = e * CAP + m0;
#pragma unroll
  for (int mt2 = 0; mt2 < 4; mt2++)
#pragma unroll
    for (int nt = 0; nt < 4; nt++)
#pragma unroll
      for (int r = 0; r < 4; r++) {
        int row = wm * 64 + mt2 * 16 + quad * 4 + r;
        int col = ntile * 128 + wn * 64 + nt * 16 + ln;
        u[(size_t)(slot0 + row) * KR + col] = f2bf(acc[mt2][nt][r]);
      }
}

// K2 (chunk c): h[slot, 512] = gelu( u @ B1c[:, c*512 : +512] )   B = V1
__global__ __launch_bounds__(256) void k2_h(
    const u16* __restrict__ u, const int* __restrict__ cnt,
    const u16* __restrict__ V1, u16* __restrict__ h, int c) {
  __shared__ __align__(16) u16 As[8192], Bs[8192];
  int bid = blockIdx.x;
  int ntile = bid & 3, gm = bid >> 2;
  int e = gm / MT_E, mt = gm % MT_E;
  int m0 = mt << 7;
  int cntE = cnt[e];
  if (m0 >= cntE) return;
  int tid = threadIdx.x;
  int slot0 = e * CAP + m0;
  const u16* Abase = u + (size_t)slot0 * KR;
  const u16* Bbase = V1 + (size_t)e * DFF * KR + (size_t)(c * 512 + ntile * 128) * KR;
  int wv = tid >> 6, lane = tid & 63;
  int wm = wv >> 1, wn = wv & 1, ln = lane & 15, quad = lane >> 4;
  f32x4 acc[4][4];
#pragma unroll
  for (int a = 0; a < 4; a++)
#pragma unroll
    for (int b = 0; b < 4; b++) acc[a][b] = (f32x4){0.f, 0.f, 0.f, 0.f};
  for (int k0 = 0; k0 < KR; k0 += 64) {
    stage_tile(Abase + k0, KR, As, tid);
    stage_tile(Bbase + k0, KR, Bs, tid);
    __syncthreads();
    mfma_block(As, Bs, acc, wm, wn, ln, quad);
    __syncthreads();
  }
#pragma unroll
  for (int mt2 = 0; mt2 < 4; mt2++)
#pragma unroll
    for (int nt = 0; nt < 4; nt++)
#pragma unroll
      for (int r = 0; r < 4; r++) {
        int row = wm * 64 + mt2 * 16 + quad * 4 + r;
        int col = ntile * 128 + wn * 64 + nt * 16 + ln;
        float v = acc[mt2][nt][r];
        float s = 1.f / (1.f + __expf(-1.702f * v));
        h[(size_t)(slot0 + row) * 512 + col] = f2bf(v * s);
      }
}

// K3 (chunk c): t[slot,256] (+)= h @ A2c[c*512.. , :]   B = W2 cols c*512..; t bf16
__global__ __launch_bounds__(256) void k3_t(
    const u16* __restrict__ h, const int* __restrict__ cnt,
    const u16* __restrict__ W2, u16* __restrict__ t, int c, int beta) {
  __shared__ __align__(16) u16 As[8192], Bs[8192];
  int bid = blockIdx.x;
  int ntile = bid & 1, gm = bid >> 1;
  int e = gm / MT_E, mt = gm % MT_E;
  int m0 = mt << 7;
  int cntE = cnt[e];
  if (m0 >= cntE) return;
  int tid = threadIdx.x;
  int slot0 = e * CAP + m0;
  const u16* Abase = h + (size_t)slot0 * 512;
  const u16* Bbase = W2 + (size_t)e * KR * DFF + (size_t)(ntile * 128) * DFF + c * 512;
  int wv = tid >> 6, lane = tid & 63;
  int wm = wv >> 1, wn = wv & 1, ln = lane & 15, quad = lane >> 4;
  f32x4 acc[4][4];
#pragma unroll
  for (int a = 0; a < 4; a++)
#pragma unroll
    for (int b = 0; b < 4; b++) acc[a][b] = (f32x4){0.f, 0.f, 0.f, 0.f};
  for (int k0 = 0; k0 < 512; k0 += 64) {
    stage_tile(Abase + k0, 512, As, tid);
    stage_tile(Bbase + k0, DFF, Bs, tid);
    __syncthreads();
    mfma_block(As, Bs, acc, wm, wn, ln, quad);
    __syncthreads();
  }
#pragma unroll
  for (int mt2 = 0; mt2 < 4; mt2++)
#pragma unroll
    for (int nt = 0; nt < 4; nt++)
#pragma unroll
      for (int r = 0; r < 4; r++) {
        int row = wm * 64 + mt2 * 16 + quad * 4 + r;
        int col = ntile * 128 + wn * 64 + nt * 16 + ln;
        u16* tp = t + (size_t)(slot0 + row) * KR + col;
        float v = acc[mt2][nt][r];
        if (beta) v += bf2f(*tp);
        *tp = f2bf(v);
      }
}

// K4: y[slot, 512] = gate * (t @ B2c)   (no atomics; coalesced bf16 writes)
__global__ __launch_bounds__(256) void k4_y(
    const u16* __restrict__ t, const int* __restrict__ cnt,
    const int* __restrict__ perm, const float* __restrict__ gate,
    const u16* __restrict__ V2, u16* __restrict__ y) {
  __shared__ __align__(16) u16 As[8192], Bs[8192];
  __shared__ float g_s[128];
  int bid = blockIdx.x;
  int ntile = bid & 3, gm = bid >> 2;
  int e = gm / MT_E, mt = gm % MT_E;
  int m0 = mt << 7;
  int cntE = cnt[e];
  if (m0 >= cntE) return;
  int tid = threadIdx.x;
  if (tid < 128) {
    int mm = m0 + tid; if (mm > cntE - 1) mm = cntE - 1;
    int tk = perm[e * T_TOK + mm];
    g_s[tid] = gate[e * T_TOK + tk];
  }
  __syncthreads();
  int slot0 = e * CAP + m0;
  const u16* Abase = t + (size_t)slot0 * KR;
  const u16* Bbase = V2 + (size_t)e * DM * KR + (size_t)(ntile * 128) * KR;
  int wv = tid >> 6, lane = tid & 63;
  int wm = wv >> 1, wn = wv & 1, ln = lane & 15, quad = lane >> 4;
  f32x4 acc[4][4];
#pragma unroll
  for (int a = 0; a < 4; a++)
#pragma unroll
    for (int b = 0; b < 4; b++) acc[a][b] = (f32x4){0.f, 0.f, 0.f, 0.f};
  for (int k0 = 0; k0 < KR; k0 += 64) {
    stage_tile(Abase + k0, KR, As, tid);
    stage_tile(Bbase + k0, KR, Bs, tid);
    __syncthreads();
    mfma_block(As, Bs, acc, wm, wn, ln, quad);
    __syncthreads();
  }
#pragma unroll
  for (int mt2 = 0; mt2 < 4; mt2++)
#pragma unroll
    for (int nt = 0; nt < 4; nt++)
#pragma unroll
      for (int r = 0; r < 4; r++) {
        int row = wm * 64 + mt2 * 16 + quad * 4 + r;
        int col = ntile * 128 + wn * 64 + nt * 16 + ln;
        y[(size_t)(slot0 + row) * DM + col] = f2bf(acc[mt2][nt][r] * g_s[row]);
      }
}

// gather: out[t] = y[slotA] + y[slotB]
__global__ void gather_kernel(const u16* __restrict__ y, const int* __restrict__ slots,
                              float* __restrict__ out) {
  int idx = blockIdx.x * 256 + threadIdx.x;   // one float4 of out per thread
  int t = idx >> 7, c4 = (idx & 127) * 4;
  int sA = slots[t * 2], sB = slots[t * 2 + 1];
  u16x4v a = *(const u16x4v*)&y[(size_t)sA * DM + c4];
  u16x4v b = *(const u16x4v*)&y[(size_t)sB * DM + c4];
  float4 o;
  o.x = bf2f(a[0]) + bf2f(b[0]);
  o.y = bf2f(a[1]) + bf2f(b[1]);
  o.z = bf2f(a[2]) + bf2f(b[2]);
  o.w = bf2f(a[3]) + bf2f(b[3]);
  *(float4*)&out[(size_t)t * DM + c4] = o;
}

// ---------------- launch ----------------
extern "C" void kernel_launch(void* const* d_in, const int* in_sizes, int n_in,
                              void* d_out, int out_size, void* d_ws, size_t ws_size,
                              hipStream_t stream) {
  const float* x   = (const float*)d_in[0];
  const float* Wr  = (const float*)d_in[1];
  const float* fc1 = (const float*)d_in[2];
  const float* fc2 = (const float*)d_in[3];
  const float* A1  = (const float*)d_in[4];
  const float* B1  = (const float*)d_in[5];
  const float* A2  = (const float*)d_in[6];
  const float* B2  = (const float*)d_in[7];
  float* out = (float*)d_out;

  char* ws = (char*)d_ws;
  float* sw1     = (float*)(ws + 0);
  int*   idx1    = (int*)(ws + 512);
  float* sw2     = (float*)(ws + 1024);
  int*   idx2    = (int*)(ws + 1536);
  int*   cnt     = (int*)(ws + 2048);
  float* probsum = (float*)(ws + 2560);
  int*   eidx    = (int*)(ws + 8192);                      // 64 KB
  int*   slots   = (int*)(ws + 8192 + 65536);              // 128 KB
  float* gate    = (float*)(ws + 8192 + 65536 + 131072);   // 512 KB
  int*   perm    = (int*)(ws + 8192 + 65536 + 131072 + 524288); // 512 KB
  u16*   W1      = (u16*)(ws + 8192 + 65536 + 131072 + 2 * 524288);
  u16*   V1      = W1 + 1048576;
  u16*   W2      = V1 + 4194304;
  u16*   V2      = W2 + 4194304;
  char*  endW    = (char*)(V2 + 1048576);                    // ~22.2 MB
  u16*   u_buf   = (u16*)endW;                               // 49152x256 bf16 = 25.2 MB
  u16*   h_buf   = (u16*)(endW + 25165824);                  // 49152x512 bf16 = 50.3 MB
  u16*   t_buf   = (u16*)(endW + 25165824 + 50331648);       // 49152x256 bf16 = 25.2 MB
  u16*   y_buf   = h_buf;   // alias: h dead after last k3; y = 49152x512 bf16 (same size)
  // total ws use ≈ 123 MB (< 148 MB known-good from rounds 3-5)

  zero_kernel<<<3, 256, 0, stream>>>(cnt, probsum);
  compose_meta<<<1, 64, 0, stream>>>(fc1, fc2, sw1, idx1, sw2, idx2);
  build_AT<<<32 * (DM / 64), 256, 0, stream>>>(A1, idx1, sw1, W1, DM);
  build_AT<<<32 * (DFF / 64), 256, 0, stream>>>(A2, idx2, sw2, W2, DFF);
  build_V<<<20480, 256, 0, stream>>>(B1, B2, sw1, idx1, sw2, idx2, V1, V2);
  router_kernel<<<T_TOK / 64, 256, 0, stream>>>(x, Wr, probsum, eidx, gate);
  scatter_kernel<<<T_TOK / 256, 256, 0, stream>>>(eidx, cnt, perm, slots);
  aux_kernel<<<1, 64, 0, stream>>>(cnt, probsum, out + (out_size - 1));

  k1_u<<<2 * NE * MT_E, 256, 0, stream>>>(x, cnt, perm, W1, u_buf);
  for (int c = 0; c < 4; c++) {
    k2_h<<<4 * NE * MT_E, 256, 0, stream>>>(u_buf, cnt, V1, h_buf, c);
    k3_t<<<2 * NE * MT_E, 256, 0, stream>>>(h_buf, cnt, W2, t_buf, c, c > 0 ? 1 : 0);
  }
  k4_y<<<4 * NE * MT_E, 256, 0, stream>>>(t_buf, cnt, perm, gate, V2, y_buf);
  gather_kernel<<<T_TOK * DM / 4 / 256, 256, 0, stream>>>(y_buf, slots, out);
}

// Round 8
// 516.265 us; speedup vs baseline: 1.5557x; 1.0122x over previous
//
#include <hip/hip_runtime.h>

// ---------------- problem constants ----------------
#define T_TOK 16384
#define DM    512
#define DFF   2048
#define NE    8
#define NP    16
#define KP    4
#define RANK  64
#define KR    256           // KP * RANK
#define EPSF  1e-8f
#define CAP   6144          // per-expert pair capacity (expected ~4096)
#define MT_E  48            // CAP / 128 M-tiles per expert

typedef unsigned short u16;
typedef __bf16 bf16x8 __attribute__((ext_vector_type(8)));
typedef float  f32x4  __attribute__((ext_vector_type(4)));
typedef unsigned short u16x8v __attribute__((ext_vector_type(8)));
typedef unsigned short u16x4v __attribute__((ext_vector_type(4)));

typedef __attribute__((address_space(3))) void as3_void;
typedef __attribute__((address_space(1))) void as1_void;

__device__ __forceinline__ u16 f2bf(float f) {
  unsigned int u = __builtin_bit_cast(unsigned int, f);
  u += 0x7fffu + ((u >> 16) & 1u);          // round-to-nearest-even
  return (u16)(u >> 16);
}
__device__ __forceinline__ float bf2f(u16 v) {
  unsigned int u = ((unsigned int)v) << 16;
  return __builtin_bit_cast(float, u);
}

__device__ __forceinline__ void gl_lds16(const u16* g, u16* l) {
  __builtin_amdgcn_global_load_lds((as1_void*)g, (as3_void*)l, 16, 0, 0);
}

// stage 128x64 bf16 tile into contig LDS (global_load_lds, wave-uniform dst)
__device__ __forceinline__ void stage_tile(const u16* g, int ld, u16* lds_tile, int tid) {
  int row = tid >> 3, c8 = (tid & 7) * 8;
#pragma unroll
  for (int ri = 0; ri < 4; ri++)
    gl_lds16(g + (size_t)(ri * 32 + row) * ld + c8, &lds_tile[(ri * 32 + row) * 64 + c8]);
}

// shared 128x128 MFMA inner step over one BK=64 LDS tile pair (256-thr kernels)
__device__ __forceinline__ void mfma_block(const u16* As, const u16* Bs, f32x4 acc[4][4],
                                           int wm, int wn, int ln, int quad) {
#pragma unroll
  for (int ks = 0; ks < 2; ks++) {
    bf16x8 af[4], bf[4];
#pragma unroll
    for (int mt = 0; mt < 4; mt++)
      af[mt] = *(const bf16x8*)&As[(wm * 64 + mt * 16 + ln) * 64 + ks * 32 + quad * 8];
#pragma unroll
    for (int nt = 0; nt < 4; nt++)
      bf[nt] = *(const bf16x8*)&Bs[(wn * 64 + nt * 16 + ln) * 64 + ks * 32 + quad * 8];
#pragma unroll
    for (int mt = 0; mt < 4; mt++)
#pragma unroll
      for (int nt = 0; nt < 4; nt++)
        acc[mt][nt] = __builtin_amdgcn_mfma_f32_16x16x32_bf16(af[mt], bf[nt], acc[mt][nt], 0, 0, 0);
  }
}

// ---------------- zero counters ----------------
__global__ void zero_kernel(int* __restrict__ cnt, float* __restrict__ probsum) {
  int i = blockIdx.x * 256 + threadIdx.x;
  if (i < NE) cnt[i] = 0;
  if (i >= NE && i < NE + NE * 64) probsum[i - NE] = 0.f;
}

// ---------------- primitive-bank softmax + top-4 ----------------
__global__ void compose_meta(const float* __restrict__ fc1, const float* __restrict__ fc2,
                             float* __restrict__ sw1, int* __restrict__ idx1,
                             float* __restrict__ sw2, int* __restrict__ idx2) {
  int tid = threadIdx.x;
  if (tid >= 16) return;
  const float* src = (tid < 8) ? fc1 : fc2;
  float* sw = (tid < 8) ? sw1 : sw2;
  int*  idx = (tid < 8) ? idx1 : idx2;
  int e = tid & 7;
  float wv[NP];
  float mx = -1e30f;
  for (int p = 0; p < NP; p++) { wv[p] = src[e * NP + p]; mx = fmaxf(mx, wv[p]); }
  float sum = 0.f;
  for (int p = 0; p < NP; p++) { wv[p] = __expf(wv[p] - mx); sum += wv[p]; }
  float inv = 1.f / sum;
  for (int p = 0; p < NP; p++) wv[p] *= inv;
  float tw[KP]; int ti[KP];
  for (int k = 0; k < KP; k++) {
    int best = 0; float bv = -1.f;
    for (int p = 0; p < NP; p++) if (wv[p] > bv) { bv = wv[p]; best = p; }
    tw[k] = bv; ti[k] = best; wv[best] = -2.f;
  }
  float ts = tw[0] + tw[1] + tw[2] + tw[3];
  float invt = 1.f / (ts + EPSF);
  for (int k = 0; k < KP; k++) {
    sw[e * KP + k] = sqrtf(tw[k] * invt + EPSF);
    idx[e * KP + k] = ti[k];
  }
}

// ---------------- build W1/W2 via LDS transpose ----------------
__global__ __launch_bounds__(256) void build_AT(
    const float* __restrict__ A, const int* __restrict__ idx,
    const float* __restrict__ sw, u16* __restrict__ W, int D) {
  __shared__ u16 T[64 * 68];
  int ntile = D >> 6;
  int dt = blockIdx.x % ntile;
  int g  = blockIdx.x / ntile;      // e*4+k
  int p = idx[g]; float s = sw[g];
  int d0 = dt * 64;
  int tid = threadIdx.x;
  {
    int rr = (tid & 15) * 4, dd = tid >> 4;
#pragma unroll
    for (int pass = 0; pass < 4; pass++) {
      int d = pass * 16 + dd;
      float4 v = *(const float4*)(A + ((size_t)p * D + d0 + d) * 64 + rr);
      T[(rr + 0) * 68 + d] = f2bf(v.x * s);
      T[(rr + 1) * 68 + d] = f2bf(v.y * s);
      T[(rr + 2) * 68 + d] = f2bf(v.z * s);
      T[(rr + 3) * 68 + d] = f2bf(v.w * s);
    }
  }
  __syncthreads();
  int e = g >> 2, k = g & 3;
  int c = (tid & 15) * 4, r = tid >> 4;
#pragma unroll
  for (int pass = 0; pass < 4; pass++) {
    int rr = pass * 16 + r;
    u16x4v o;
#pragma unroll
    for (int j = 0; j < 4; j++) o[j] = T[rr * 68 + c + j];
    *(u16x4v*)&W[((size_t)e * KR + k * 64 + rr) * D + d0 + c] = o;
  }
}

// ---------------- build V1/V2 ----------------
__global__ void build_V(const float* __restrict__ B1, const float* __restrict__ B2,
                        const float* __restrict__ sw1, const int* __restrict__ idx1,
                        const float* __restrict__ sw2, const int* __restrict__ idx2,
                        u16* __restrict__ V1, u16* __restrict__ V2) {
  const int S2 = NE * DFF * KR;   // V1[e][f][kr] = B1[p][r][f]*s
  const int S4 = NE * DM * KR;    // V2[e][d][kr] = B2[p][r][d]*s
  int i = blockIdx.x * 256 + threadIdx.x;
  if (i < S2) {
    int kr = i & 255; int f = (i >> 8) & 2047; int e = i >> 19;
    int k = kr >> 6, r = kr & 63; int p = idx1[e * 4 + k];
    V1[i] = f2bf(B1[((size_t)p * RANK + r) * DFF + f] * sw1[e * 4 + k]);
  } else if (i < S2 + S4) {
    int j = i - S2;
    int kr = j & 255; int d = (j >> 8) & 511; int e = j >> 17;
    int k = kr >> 6, r = kr & 63; int p = idx2[e * 4 + k];
    V2[j] = f2bf(B2[((size_t)p * RANK + r) * DM + d] * sw2[e * 4 + k]);
  }
}

// ---------------- router, token-per-lane (k-split 4) ----------------
__global__ __launch_bounds__(256) void router_kernel(
    const float* __restrict__ x, const float* __restrict__ Wr,
    float* __restrict__ probsum, int* __restrict__ eidx,
    float* __restrict__ gate) {
  __shared__ float wr_s[NE * 4 * 132];
  __shared__ float ps_s[NE];
  int tid = threadIdx.x;
  if (tid < NE) ps_s[tid] = 0.f;
  for (int i = tid; i < NE * DM; i += 256) {
    int e = i >> 9, k = i & 511;
    wr_s[(e * 4 + (k >> 7)) * 132 + (k & 127)] = Wr[i];
  }
  __syncthreads();
  int lane = tid & 63, wv = tid >> 6;
  int tl = lane & 15, sl = lane >> 4;
  int t = blockIdx.x * 64 + wv * 16 + tl;
  const float* xp = x + (size_t)t * DM + sl * 128;
  const float* wp = &wr_s[sl * 132];
  float acc[NE];
#pragma unroll
  for (int e = 0; e < NE; e++) acc[e] = 0.f;
  for (int c = 0; c < 32; c++) {
    float4 xv = *(const float4*)(xp + c * 4);
#pragma unroll
    for (int e = 0; e < NE; e++) {
      float4 w4 = *(const float4*)(wp + e * 4 * 132 + c * 4);
      acc[e] += xv.x * w4.x + xv.y * w4.y + xv.z * w4.z + xv.w * w4.w;
    }
  }
#pragma unroll
  for (int e = 0; e < NE; e++) {
    acc[e] += __shfl_xor(acc[e], 16, 64);
    acc[e] += __shfl_xor(acc[e], 32, 64);
  }
  if (sl == 0) {
    float mx = acc[0];
#pragma unroll
    for (int e = 1; e < NE; e++) mx = fmaxf(mx, acc[e]);
    float pe[NE]; float sum = 0.f;
#pragma unroll
    for (int e = 0; e < NE; e++) { pe[e] = __expf(acc[e] - mx); sum += pe[e]; }
    float inv = 1.f / sum;
#pragma unroll
    for (int e = 0; e < NE; e++) pe[e] *= inv;
    int i0 = 0;
#pragma unroll
    for (int e = 1; e < NE; e++) if (pe[e] > pe[i0]) i0 = e;
    int i1 = (i0 == 0) ? 1 : 0;
#pragma unroll
    for (int e = 0; e < NE; e++) if (e != i0 && pe[e] > pe[i1]) i1 = e;
    float p0 = pe[i0], p1 = pe[i1];
    float gd = 1.f / (p0 + p1 + EPSF);
    eidx[t] = i0 | (i1 << 3);
    gate[i0 * T_TOK + t] = p0 * gd;
    gate[i1 * T_TOK + t] = p1 * gd;
#pragma unroll
    for (int e = 0; e < NE; e++) atomicAdd(&ps_s[e], pe[e]);
  }
  __syncthreads();
  if (tid < NE) atomicAdd(&probsum[tid * 64 + (blockIdx.x & 63)], ps_s[tid]);
}

// ---------------- scatter (block-aggregated cnt) + per-token slot pairs ----------
__global__ void scatter_kernel(const int* __restrict__ eidx,
                               int* __restrict__ cnt, int* __restrict__ perm,
                               int* __restrict__ slots) {
  __shared__ int hist[NE], base[NE];
  int tid = threadIdx.x;
  if (tid < NE) hist[tid] = 0;
  __syncthreads();
  int t = blockIdx.x * 256 + tid;
  int pk = eidx[t];
  int e0 = pk & 7, e1 = (pk >> 3) & 7;
  int p0 = atomicAdd(&hist[e0], 1);
  int p1 = atomicAdd(&hist[e1], 1);
  __syncthreads();
  if (tid < NE) base[tid] = atomicAdd(&cnt[tid], hist[tid]);
  __syncthreads();
  int g0 = base[e0] + p0; if (g0 >= CAP) g0 = CAP - 1;
  int g1 = base[e1] + p1; if (g1 >= CAP) g1 = CAP - 1;
  perm[e0 * T_TOK + g0] = t;
  perm[e1 * T_TOK + g1] = t;
  slots[t * 2]     = e0 * CAP + g0;
  slots[t * 2 + 1] = e1 * CAP + g1;
}

// ---------------- aux loss (one wave) ----------------
__global__ void aux_kernel(const int* __restrict__ cnt, const float* __restrict__ probsum,
                           float* __restrict__ aux_out) {
  int lane = threadIdx.x;
  if (lane >= 64) return;
  float s[NE];
#pragma unroll
  for (int e = 0; e < NE; e++) {
    float v = probsum[e * 64 + lane];
#pragma unroll
    for (int off = 32; off > 0; off >>= 1) v += __shfl_xor(v, off, 64);
    s[e] = v;
  }
  if (lane == 0) {
    float c[NE]; float cs = 0.f;
    for (int e = 0; e < NE; e++) { c[e] = (float)cnt[e]; cs += c[e]; }
    float aux = 0.f;
    for (int e = 0; e < NE; e++)
      aux += (c[e] / (cs + EPSF)) * (s[e] / (float)T_TOK);
    *aux_out = (float)NE * aux;
  }
}

// ================= FFN pipeline =================
// K1: u[slot,256] = bf16( gather(x) @ A1c )
__global__ __launch_bounds__(256) void k1_u(
    const float* __restrict__ x, const int* __restrict__ cnt,
    const int* __restrict__ perm, const u16* __restrict__ W1,
    u16* __restrict__ u) {
  __shared__ __align__(16) u16 As[8192], Bs[8192];
  __shared__ int tok_s[128];
  int bid = blockIdx.x;
  int ntile = bid & 1, gm = bid >> 1;
  int e = gm / MT_E, mt = gm % MT_E;
  int m0 = mt << 7;
  int cntE = cnt[e];
  if (m0 >= cntE) return;
  int tid = threadIdx.x;
  if (tid < 128) {
    int mm = m0 + tid; if (mm > cntE - 1) mm = cntE - 1;
    tok_s[tid] = perm[e * T_TOK + mm];
  }
  __syncthreads();
  const u16* Bbase = W1 + (size_t)e * KR * DM + (size_t)(ntile * 128) * DM;
  int wv = tid >> 6, lane = tid & 63;
  int wm = wv >> 1, wn = wv & 1, ln = lane & 15, quad = lane >> 4;
  f32x4 acc[4][4];
#pragma unroll
  for (int a = 0; a < 4; a++)
#pragma unroll
    for (int b = 0; b < 4; b++) acc[a][b] = (f32x4){0.f, 0.f, 0.f, 0.f};
  for (int k0 = 0; k0 < DM; k0 += 64) {
    for (int i = tid; i < 2048; i += 256) {
      int row = i >> 4, c4 = i & 15;
      float4 v = *(const float4*)(x + (size_t)tok_s[row] * DM + k0 + c4 * 4);
      u16x4v o; o[0] = f2bf(v.x); o[1] = f2bf(v.y); o[2] = f2bf(v.z); o[3] = f2bf(v.w);
      *(u16x4v*)&As[row * 64 + c4 * 4] = o;
    }
    stage_tile(Bbase + k0, DM, Bs, tid);
    __syncthreads();
    mfma_block(As, Bs, acc, wm, wn, ln, quad);
    __syncthreads();
  }
  int slot0 = e * CAP + m0;
#pragma unroll
  for (int mt2 = 0; mt2 < 4; mt2++)
#pragma unroll
    for (int nt = 0; nt < 4; nt++)
#pragma unroll
      for (int r = 0; r < 4; r++) {
        int row = wm * 64 + mt2 * 16 + quad * 4 + r;
        int col = ntile * 128 + wn * 64 + nt * 16 + ln;
        u[(size_t)(slot0 + row) * KR + col] = f2bf(acc[mt2][nt][r]);
      }
}

// K23 v2: t[slot, 256] = gelu(u @ B1c) @ A2c   — h never leaves LDS, t written once.
// M-tile 64, 256 thr. LDS: Us 32K + Bs 16K + Hs(stride 132, conflict-free) 16.9K
// = 64.5 KB -> 2 blocks/CU. Round-6 failure modes (1 blk/CU, 8-way Hs write
// conflicts at stride 128) engineered out.
__global__ __launch_bounds__(256, 2) void k23(
    const u16* __restrict__ u, const int* __restrict__ cnt,
    const u16* __restrict__ V1, const u16* __restrict__ W2,
    u16* __restrict__ t) {
  __shared__ __align__(16) u16 Us[64 * 256];   // 32 KB, u tile resident
  __shared__ __align__(16) u16 Bs[128 * 64];   // 16 KB staging (V1 / W2 chunks)
  __shared__ __align__(16) u16 Hs[64 * 132];   // 16.9 KB, padded stride
  int bid = blockIdx.x;
  int e = bid / (CAP / 64), mt = bid % (CAP / 64);
  int m0 = mt << 6;
  int cntE = cnt[e];
  if (m0 >= cntE) return;
  int tid = threadIdx.x;
  int slot0 = e * CAP + m0;
  const u16* ub  = u + (size_t)slot0 * KR;
  const u16* V1e = V1 + (size_t)e * DFF * KR;
  const u16* W2e = W2 + (size_t)e * KR * DFF;
  // stage u tile: source and dest both linear (row stride == 256) -> one 32KB copy
#pragma unroll
  for (int r = 0; r < 8; r++) {
    int i = r * 256 + tid;
    gl_lds16(ub + i * 8, &Us[i * 8]);
  }
  int wv = tid >> 6, lane = tid & 63;
  int ln = lane & 15, quad = lane >> 4;
  f32x4 tacc[4][4];   // [mt][hh*2+nt] ; wave wv owns t cols hh*128 + wv*32 + nt*16 + ln
#pragma unroll
  for (int a = 0; a < 4; a++)
#pragma unroll
    for (int b = 0; b < 4; b++) tacc[a][b] = (f32x4){0.f, 0.f, 0.f, 0.f};

  for (int f0 = 0; f0 < DFF; f0 += 128) {
    // ---- phase A: h(64x128) = u @ V1[f0:f0+128,:]^T ----
    f32x4 hacc[4][2];
#pragma unroll
    for (int a = 0; a < 4; a++)
#pragma unroll
      for (int b = 0; b < 2; b++) hacc[a][b] = (f32x4){0.f, 0.f, 0.f, 0.f};
    for (int k0 = 0; k0 < 4; k0++) {
      __syncthreads();                               // Bs free (also drains Us stage @f0=0,k0=0)
      stage_tile(V1e + (size_t)f0 * KR + k0 * 64, KR, Bs, tid);
      __syncthreads();
#pragma unroll
      for (int ks = 0; ks < 2; ks++) {
        bf16x8 af[4], bf[2];
#pragma unroll
        for (int m = 0; m < 4; m++)
          af[m] = *(const bf16x8*)&Us[(m * 16 + ln) * 256 + k0 * 64 + ks * 32 + quad * 8];
#pragma unroll
        for (int nt = 0; nt < 2; nt++)
          bf[nt] = *(const bf16x8*)&Bs[(wv * 32 + nt * 16 + ln) * 64 + ks * 32 + quad * 8];
#pragma unroll
        for (int m = 0; m < 4; m++)
#pragma unroll
          for (int nt = 0; nt < 2; nt++)
            hacc[m][nt] = __builtin_amdgcn_mfma_f32_16x16x32_bf16(af[m], bf[nt], hacc[m][nt], 0, 0, 0);
      }
    }
    // gelu -> Hs (stride 132: quads 8 banks apart, ln-group 2-way -> conflict-free)
#pragma unroll
    for (int m = 0; m < 4; m++)
#pragma unroll
      for (int nt = 0; nt < 2; nt++)
#pragma unroll
        for (int r = 0; r < 4; r++) {
          int row = m * 16 + quad * 4 + r;
          int col = wv * 32 + nt * 16 + ln;
          float v = hacc[m][nt][r];
          float s = 1.f / (1.f + __expf(-1.702f * v));
          Hs[row * 132 + col] = f2bf(v * s);
        }
    // ---- phase B: t(64x256) += h @ W2[:, f0:f0+128]^T ----
#pragma unroll
    for (int hh = 0; hh < 2; hh++)
#pragma unroll
      for (int fi = 0; fi < 2; fi++) {
        __syncthreads();                             // Hs written / Bs free
        stage_tile(W2e + (size_t)(hh * 128) * DFF + f0 + fi * 64, DFF, Bs, tid);
        __syncthreads();
#pragma unroll
        for (int ks = 0; ks < 2; ks++) {
          bf16x8 af[4], bf[2];
#pragma unroll
          for (int m = 0; m < 4; m++)
            af[m] = *(const bf16x8*)&Hs[(m * 16 + ln) * 132 + fi * 64 + ks * 32 + quad * 8];
#pragma unroll
          for (int nt = 0; nt < 2; nt++)
            bf[nt] = *(const bf16x8*)&Bs[(wv * 32 + nt * 16 + ln) * 64 + ks * 32 + quad * 8];
#pragma unroll
          for (int m = 0; m < 4; m++)
#pragma unroll
            for (int nt = 0; nt < 2; nt++)
              tacc[m][hh * 2 + nt] = __builtin_amdgcn_mfma_f32_16x16x32_bf16(af[m], bf[nt], tacc[m][hh * 2 + nt], 0, 0, 0);
        }
      }
  }
  // epilogue: t (bf16, written once — no RMW)
#pragma unroll
  for (int m = 0; m < 4; m++)
#pragma unroll
    for (int hh = 0; hh < 2; hh++)
#pragma unroll
      for (int nt = 0; nt < 2; nt++)
#pragma unroll
        for (int r = 0; r < 4; r++) {
          int row = m * 16 + quad * 4 + r;
          int col = hh * 128 + wv * 32 + nt * 16 + ln;
          t[(size_t)(slot0 + row) * KR + col] = f2bf(tacc[m][hh * 2 + nt][r]);
        }
}

// K4: y[slot, 512] = gate * (t @ B2c)
__global__ __launch_bounds__(256) void k4_y(
    const u16* __restrict__ t, const int* __restrict__ cnt,
    const int* __restrict__ perm, const float* __restrict__ gate,
    const u16* __restrict__ V2, u16* __restrict__ y) {
  __shared__ __align__(16) u16 As[8192], Bs[8192];
  __shared__ float g_s[128];
  int bid = blockIdx.x;
  int ntile = bid & 3, gm = bid >> 2;
  int e = gm / MT_E, mt = gm % MT_E;
  int m0 = mt << 7;
  int cntE = cnt[e];
  if (m0 >= cntE) return;
  int tid = threadIdx.x;
  if (tid < 128) {
    int mm = m0 + tid; if (mm > cntE - 1) mm = cntE - 1;
    int tk = perm[e * T_TOK + mm];
    g_s[tid] = gate[e * T_TOK + tk];
  }
  __syncthreads();
  int slot0 = e * CAP + m0;
  const u16* Abase = t + (size_t)slot0 * KR;
  const u16* Bbase = V2 + (size_t)e * DM * KR + (size_t)(ntile * 128) * KR;
  int wv = tid >> 6, lane = tid & 63;
  int wm = wv >> 1, wn = wv & 1, ln = lane & 15, quad = lane >> 4;
  f32x4 acc[4][4];
#pragma unroll
  for (int a = 0; a < 4; a++)
#pragma unroll
    for (int b = 0; b < 4; b++) acc[a][b] = (f32x4){0.f, 0.f, 0.f, 0.f};
  for (int k0 = 0; k0 < KR; k0 += 64) {
    stage_tile(Abase + k0, KR, As, tid);
    stage_tile(Bbase + k0, KR, Bs, tid);
    __syncthreads();
    mfma_block(As, Bs, acc, wm, wn, ln, quad);
    __syncthreads();
  }
#pragma unroll
  for (int mt2 = 0; mt2 < 4; mt2++)
#pragma unroll
    for (int nt = 0; nt < 4; nt++)
#pragma unroll
      for (int r = 0; r < 4; r++) {
        int row = wm * 64 + mt2 * 16 + quad * 4 + r;
        int col = ntile * 128 + wn * 64 + nt * 16 + ln;
        y[(size_t)(slot0 + row) * DM + col] = f2bf(acc[mt2][nt][r] * g_s[row]);
      }
}

// gather: out[t] = y[slotA] + y[slotB]
__global__ void gather_kernel(const u16* __restrict__ y, const int* __restrict__ slots,
                              float* __restrict__ out) {
  int idx = blockIdx.x * 256 + threadIdx.x;
  int t = idx >> 7, c4 = (idx & 127) * 4;
  int sA = slots[t * 2], sB = slots[t * 2 + 1];
  u16x4v a = *(const u16x4v*)&y[(size_t)sA * DM + c4];
  u16x4v b = *(const u16x4v*)&y[(size_t)sB * DM + c4];
  float4 o;
  o.x = bf2f(a[0]) + bf2f(b[0]);
  o.y = bf2f(a[1]) + bf2f(b[1]);
  o.z = bf2f(a[2]) + bf2f(b[2]);
  o.w = bf2f(a[3]) + bf2f(b[3]);
  *(float4*)&out[(size_t)t * DM + c4] = o;
}

// ---------------- launch ----------------
extern "C" void kernel_launch(void* const* d_in, const int* in_sizes, int n_in,
                              void* d_out, int out_size, void* d_ws, size_t ws_size,
                              hipStream_t stream) {
  const float* x   = (const float*)d_in[0];
  const float* Wr  = (const float*)d_in[1];
  const float* fc1 = (const float*)d_in[2];
  const float* fc2 = (const float*)d_in[3];
  const float* A1  = (const float*)d_in[4];
  const float* B1  = (const float*)d_in[5];
  const float* A2  = (const float*)d_in[6];
  const float* B2  = (const float*)d_in[7];
  float* out = (float*)d_out;

  char* ws = (char*)d_ws;
  float* sw1     = (float*)(ws + 0);
  int*   idx1    = (int*)(ws + 512);
  float* sw2     = (float*)(ws + 1024);
  int*   idx2    = (int*)(ws + 1536);
  int*   cnt     = (int*)(ws + 2048);
  float* probsum = (float*)(ws + 2560);
  int*   eidx    = (int*)(ws + 8192);                      // 64 KB
  int*   slots   = (int*)(ws + 8192 + 65536);              // 128 KB
  float* gate    = (float*)(ws + 8192 + 65536 + 131072);   // 512 KB
  int*   perm    = (int*)(ws + 8192 + 65536 + 131072 + 524288); // 512 KB
  u16*   W1      = (u16*)(ws + 8192 + 65536 + 131072 + 2 * 524288);
  u16*   V1      = W1 + 1048576;
  u16*   W2      = V1 + 4194304;
  u16*   V2      = W2 + 4194304;
  char*  endW    = (char*)(V2 + 1048576);                    // ~22.2 MB
  u16*   u_buf   = (u16*)endW;                               // 49152x256 bf16 = 25.2 MB
  u16*   t_buf   = (u16*)(endW + 25165824);                  // 49152x256 bf16 = 25.2 MB
  u16*   y_buf   = (u16*)(endW + 2 * 25165824);              // 49152x512 bf16 = 50.3 MB
  // total ws use ≈ 123 MB

  zero_kernel<<<3, 256, 0, stream>>>(cnt, probsum);
  compose_meta<<<1, 64, 0, stream>>>(fc1, fc2, sw1, idx1, sw2, idx2);
  build_AT<<<32 * (DM / 64), 256, 0, stream>>>(A1, idx1, sw1, W1, DM);
  build_AT<<<32 * (DFF / 64), 256, 0, stream>>>(A2, idx2, sw2, W2, DFF);
  build_V<<<20480, 256, 0, stream>>>(B1, B2, sw1, idx1, sw2, idx2, V1, V2);
  router_kernel<<<T_TOK / 64, 256, 0, stream>>>(x, Wr, probsum, eidx, gate);
  scatter_kernel<<<T_TOK / 256, 256, 0, stream>>>(eidx, cnt, perm, slots);
  aux_kernel<<<1, 64, 0, stream>>>(cnt, probsum, out + (out_size - 1));

  k1_u<<<2 * NE * MT_E, 256, 0, stream>>>(x, cnt, perm, W1, u_buf);
  k23<<<NE * (CAP / 64), 256, 0, stream>>>(u_buf, cnt, V1, W2, t_buf);
  k4_y<<<4 * NE * MT_E, 256, 0, stream>>>(t_buf, cnt, perm, gate, V2, y_buf);
  gather_kernel<<<T_TOK * DM / 4 / 256, 256, 0, stream>>>(y_buf, slots, out);
}